// Round 1
// baseline (414.069 us; speedup 1.0000x reference)
//
#include <hip/hip_runtime.h>
#include <hip/hip_bf16.h>

#define N_STATES 25
#define N_XVALS  50          // obs in [0, 50)
#define TBL_SZ   (N_STATES * N_XVALS)
#define LOG_PROBS_PRECISION -100000.0f

// Native clang vector types — __builtin_nontemporal_* rejects HIP's
// class-based int4/float4 (HIP_vector_type), but accepts these.
typedef int   i32x4 __attribute__((ext_vector_type(4)));
typedef float f32x4 __attribute__((ext_vector_type(4)));

// ---------------------------------------------------------------------------
// Kernel 1: build the 25x50 lookup table  T[s][x] = logprob(state s, obs x)
//   row 0: bookend  (x>0 ? -1e5 : 0)
//   rows 1..24: NB logpmf via exact integer-x identities:
//     gammaln(x+phi)-gammaln(phi) = sum_{j=0}^{x-1} log(phi+j)
//     gammaln(x+1)                = sum_{j=2}^{x}   log(j)
// Kept byte-identical to the verified version (absmax 0.0 depends on the
// exact serial summation order).
// ---------------------------------------------------------------------------
__global__ void build_table_kernel(const float* __restrict__ means,
                                   const float* __restrict__ phis,
                                   float* __restrict__ table) {
    int idx = blockIdx.x * blockDim.x + threadIdx.x;
    if (idx >= TBL_SZ) return;
    int s = idx / N_XVALS;
    int x = idx % N_XVALS;
    float v;
    if (s == 0) {
        v = (x > 0) ? LOG_PROBS_PRECISION : 0.0f;
    } else {
        float mu  = means[s];
        float phi = phis[s];
        float rising = 0.0f;                 // gammaln(x+phi)-gammaln(phi)
        for (int j = 0; j < x; ++j) rising += logf(phi + (float)j);
        float logfact = 0.0f;                // gammaln(x+1)
        for (int j = 2; j <= x; ++j) logfact += logf((float)j);
        float c = phi * logf(phi / (phi + mu));
        float d = logf(mu  / (phi + mu));
        v = rising - logfact + c + (float)x * d;
    }
    table[idx] = v;
}

// ---------------------------------------------------------------------------
// Kernel 2: out[s][i] = T[s][obs[i]] — gather + stream-write.
// R5 change vs R3 structure: 16 spots/thread (4 int4 groups at
// +0/+256/+512/+768 in a 1024-group block span) so each block writes a
// contiguous 16 KB run per output row (was 8 KB) — 4x fewer concurrently
// open DRAM write regions chip-wide. obs loads are issued BEFORE the LDS
// table staging so their HBM latency hides under the staging + barrier.
// No clamps: harness restores pristine obs (0..49) before every launch.
// Table in LDS (5 KB); gather conflicts mild (~2-4-way, cheap per m136).
// ---------------------------------------------------------------------------
__global__ __launch_bounds__(256) void
emit_kernel(const int* __restrict__ obs,
            const float* __restrict__ table,
            float* __restrict__ out,
            int n_groups, int n_spots) {
    __shared__ float t[TBL_SZ];

    const int g0 = blockIdx.x * 1024 + threadIdx.x;
    const int g1 = g0 + 256;
    const int g2 = g0 + 512;
    const int g3 = g0 + 768;
    const bool v0 = g0 < n_groups;
    const bool v1 = g1 < n_groups;
    const bool v2 = g2 < n_groups;
    const bool v3 = g3 < n_groups;

    // Issue all obs loads first — overlap global latency with table staging.
    i32x4 o0 = {0, 0, 0, 0}, o1 = {0, 0, 0, 0}, o2 = {0, 0, 0, 0}, o3 = {0, 0, 0, 0};
    if (v0) o0 = __builtin_nontemporal_load(((const i32x4*)obs) + g0);
    if (v1) o1 = __builtin_nontemporal_load(((const i32x4*)obs) + g1);
    if (v2) o2 = __builtin_nontemporal_load(((const i32x4*)obs) + g2);
    if (v3) o3 = __builtin_nontemporal_load(((const i32x4*)obs) + g3);

    for (int i = threadIdx.x; i < TBL_SZ; i += 256) t[i] = table[i];
    __syncthreads();

    if (!v0) return;

#pragma unroll
    for (int s = 0; s < N_STATES; ++s) {
        const float* __restrict__ row = t + s * N_XVALS;
        f32x4 w0, w1, w2, w3;
        w0.x = row[o0.x]; w0.y = row[o0.y]; w0.z = row[o0.z]; w0.w = row[o0.w];
        w1.x = row[o1.x]; w1.y = row[o1.y]; w1.z = row[o1.z]; w1.w = row[o1.w];
        w2.x = row[o2.x]; w2.y = row[o2.y]; w2.z = row[o2.z]; w2.w = row[o2.w];
        w3.x = row[o3.x]; w3.y = row[o3.y]; w3.z = row[o3.z]; w3.w = row[o3.w];
        f32x4* dst = (f32x4*)(out + (size_t)s * (size_t)n_spots);
        __builtin_nontemporal_store(w0, dst + g0);
        if (v1) __builtin_nontemporal_store(w1, dst + g1);
        if (v2) __builtin_nontemporal_store(w2, dst + g2);
        if (v3) __builtin_nontemporal_store(w3, dst + g3);
    }
}

extern "C" void kernel_launch(void* const* d_in, const int* in_sizes, int n_in,
                              void* d_out, int out_size, void* d_ws, size_t ws_size,
                              hipStream_t stream) {
    const float* means = (const float*)d_in[0];   // (25,)
    const float* phis  = (const float*)d_in[1];   // (25,)
    const int*   obs   = (const int*)d_in[2];     // (N_SPOTS,)
    float* out = (float*)d_out;                   // (25, N_SPOTS) row-major
    float* table = (float*)d_ws;                  // 1250 floats scratch

    int n_spots  = in_sizes[2];
    int n_groups = n_spots / 4;                   // 4e6 -> 1e6 int4 groups

    build_table_kernel<<<(TBL_SZ + 255) / 256, 256, 0, stream>>>(means, phis, table);

    int blocks = (n_groups + 1023) / 1024;        // 16 spots/thread
    emit_kernel<<<blocks, 256, 0, stream>>>(obs, table, out, n_groups, n_spots);
}

// Round 2
// 410.731 us; speedup vs baseline: 1.0081x; 1.0081x over previous
//
#include <hip/hip_runtime.h>
#include <hip/hip_bf16.h>

#define N_STATES 25
#define N_XVALS  50          // obs in [0, 50)
#define TBL_SZ   (N_STATES * N_XVALS)
#define LOG_PROBS_PRECISION -100000.0f

// Native clang vector types — __builtin_nontemporal_* rejects HIP's
// class-based int4/float4 (HIP_vector_type), but accepts these.
typedef int   i32x4 __attribute__((ext_vector_type(4)));
typedef float f32x4 __attribute__((ext_vector_type(4)));

// ---------------------------------------------------------------------------
// Kernel 1: build the 25x50 lookup table  T[s][x] = logprob(state s, obs x)
//   row 0: bookend  (x>0 ? -1e5 : 0)
//   rows 1..24: NB logpmf via exact integer-x identities:
//     gammaln(x+phi)-gammaln(phi) = sum_{j=0}^{x-1} log(phi+j)
//     gammaln(x+1)                = sum_{j=2}^{x}   log(j)
// Byte-identical to the verified version (absmax 0.0 depends on the exact
// serial summation order).
// ---------------------------------------------------------------------------
__global__ void build_table_kernel(const float* __restrict__ means,
                                   const float* __restrict__ phis,
                                   float* __restrict__ table) {
    int idx = blockIdx.x * blockDim.x + threadIdx.x;
    if (idx >= TBL_SZ) return;
    int s = idx / N_XVALS;
    int x = idx % N_XVALS;
    float v;
    if (s == 0) {
        v = (x > 0) ? LOG_PROBS_PRECISION : 0.0f;
    } else {
        float mu  = means[s];
        float phi = phis[s];
        float rising = 0.0f;                 // gammaln(x+phi)-gammaln(phi)
        for (int j = 0; j < x; ++j) rising += logf(phi + (float)j);
        float logfact = 0.0f;                // gammaln(x+1)
        for (int j = 2; j <= x; ++j) logfact += logf((float)j);
        float c = phi * logf(phi / (phi + mu));
        float d = logf(mu  / (phi + mu));
        v = rising - logfact + c + (float)x * d;
    }
    table[idx] = v;
}

// ---------------------------------------------------------------------------
// Kernel 2: out[s][i] = T[s][obs[i]] — gather + stream-write.
// R6: exact R3 structure (best-measured, 410.3 µs) with ONE variable changed:
// stores are plain (L2 write-combined) instead of nontemporal. The harness
// fill kernel reaches 79% of HBM peak on this same allocation with plain
// stores; nt stores were the last untested difference on the write path.
// Run-length (R5) and 25-stream pattern (prev session R4) are both falsified
// as bottlenecks. If this is neutral, emit is at the memory-system floor.
// No clamps: harness restores pristine obs (0..49) before every launch.
// Table in LDS (5 KB); gather conflicts ~2-4-way (cheap per m136).
// ---------------------------------------------------------------------------
__global__ __launch_bounds__(256) void
emit_kernel(const int* __restrict__ obs,
            const float* __restrict__ table,
            float* __restrict__ out,
            int n_groups, int n_spots) {
    __shared__ float t[TBL_SZ];
    for (int i = threadIdx.x; i < TBL_SZ; i += 256) t[i] = table[i];
    __syncthreads();

    int g0 = blockIdx.x * 512 + threadIdx.x;   // first int4 group
    int g1 = g0 + 256;                          // second, +4 KB in every stream
    if (g0 >= n_groups) return;
    bool have2 = (g1 < n_groups);

    i32x4 oa = __builtin_nontemporal_load(((const i32x4*)obs) + g0);
    i32x4 ob = have2 ? __builtin_nontemporal_load(((const i32x4*)obs) + g1)
                     : oa;

#pragma unroll
    for (int s = 0; s < N_STATES; ++s) {
        const float* row = t + s * N_XVALS;
        f32x4 va, vb;
        va.x = row[oa.x]; va.y = row[oa.y]; va.z = row[oa.z]; va.w = row[oa.w];
        vb.x = row[ob.x]; vb.y = row[ob.y]; vb.z = row[ob.z]; vb.w = row[ob.w];
        f32x4* dst = (f32x4*)(out + (size_t)s * (size_t)n_spots);
        dst[g0] = va;                            // plain store — through L2
        if (have2) dst[g1] = vb;
    }
}

extern "C" void kernel_launch(void* const* d_in, const int* in_sizes, int n_in,
                              void* d_out, int out_size, void* d_ws, size_t ws_size,
                              hipStream_t stream) {
    const float* means = (const float*)d_in[0];   // (25,)
    const float* phis  = (const float*)d_in[1];   // (25,)
    const int*   obs   = (const int*)d_in[2];     // (N_SPOTS,)
    float* out = (float*)d_out;                   // (25, N_SPOTS) row-major
    float* table = (float*)d_ws;                  // 1250 floats scratch

    int n_spots  = in_sizes[2];
    int n_groups = n_spots / 4;                   // 4e6 -> 1e6 int4 groups

    build_table_kernel<<<(TBL_SZ + 255) / 256, 256, 0, stream>>>(means, phis, table);

    int blocks = (n_groups + 511) / 512;          // 8 spots/thread
    emit_kernel<<<blocks, 256, 0, stream>>>(obs, table, out, n_groups, n_spots);
}